// Round 1
// baseline (1722.033 us; speedup 1.0000x reference)
//
#include <hip/hip_runtime.h>

typedef _Float16 f16;
typedef _Float16 f16x4 __attribute__((ext_vector_type(4)));
typedef _Float16 f16x8 __attribute__((ext_vector_type(8)));
typedef float f32x4 __attribute__((ext_vector_type(4)));

#define LSTM_B 256
#define LSTM_H 1024
#define LSTM_O 512
#define LSTM_T 128
#define GATES 4096

// ---------------- fp32 -> fp16 convert (vectorized) ----------------
__global__ void cvt4_kernel(const float4* __restrict__ src, f16x4* __restrict__ dst, int n4) {
  int i = blockIdx.x * blockDim.x + threadIdx.x;
  int st = gridDim.x * blockDim.x;
  for (; i < n4; i += st) {
    float4 v = src[i];
    f16x4 o; o[0] = (f16)v.x; o[1] = (f16)v.y; o[2] = (f16)v.z; o[3] = (f16)v.w;
    dst[i] = o;
  }
}

// ---------------- generic C[M,N] = A[MxK] * Bw[NxK]^T + bias ----------------
// 64x64 tile per WG, 4 waves as 2x2 of 32x32, BK=64, fp16 MFMA 16x16x32.
__global__ __launch_bounds__(256) void gemm_bt_kernel(
    const f16* __restrict__ A, const f16* __restrict__ Bw,
    const float* __restrict__ bias0, const float* __restrict__ bias1,
    float* __restrict__ out, int M, int N, int K, int gn)
{
  __shared__ __align__(16) f16 As[64][72];   // pad 72: 144B row stride -> <=2-way bank alias (free)
  __shared__ __align__(16) f16 Bs[64][72];
  int bx = blockIdx.x;
  int mb = bx / gn;
  int m0 = mb * 64;
  int n0 = (bx - mb * gn) * 64;
  int tid = threadIdx.x;
  int lane = tid & 63, w = tid >> 6;
  int wm = w >> 1, wn = w & 1;
  int sr = tid >> 2, sseg = tid & 3;          // staging: row, 16-f16 segment
  const f16* ga = A  + (size_t)(m0 + sr) * K + sseg * 16;
  const f16* gb = Bw + (size_t)(n0 + sr) * K + sseg * 16;
  f32x4 acc00 = {}, acc01 = {}, acc10 = {}, acc11 = {};
  f16x8 ra0 = *(const f16x8*)ga, ra1 = *(const f16x8*)(ga + 8);
  f16x8 rb0 = *(const f16x8*)gb, rb1 = *(const f16x8*)(gb + 8);
  for (int kc = 0; kc < K; kc += 64) {
    __syncthreads();
    *(f16x8*)&As[sr][sseg * 16]     = ra0;
    *(f16x8*)&As[sr][sseg * 16 + 8] = ra1;
    *(f16x8*)&Bs[sr][sseg * 16]     = rb0;
    *(f16x8*)&Bs[sr][sseg * 16 + 8] = rb1;
    __syncthreads();
    if (kc + 64 < K) {  // prefetch next chunk into regs; latency hides under MFMA phase
      ga += 64; gb += 64;
      ra0 = *(const f16x8*)ga; ra1 = *(const f16x8*)(ga + 8);
      rb0 = *(const f16x8*)gb; rb1 = *(const f16x8*)(gb + 8);
    }
    int g = lane >> 4, r = lane & 15;
    #pragma unroll
    for (int s = 0; s < 2; s++) {
      f16x8 a0 = *(const f16x8*)&As[wm * 32      + r][s * 32 + g * 8];
      f16x8 a1 = *(const f16x8*)&As[wm * 32 + 16 + r][s * 32 + g * 8];
      f16x8 b0 = *(const f16x8*)&Bs[wn * 32      + r][s * 32 + g * 8];
      f16x8 b1 = *(const f16x8*)&Bs[wn * 32 + 16 + r][s * 32 + g * 8];
      acc00 = __builtin_amdgcn_mfma_f32_16x16x32_f16(a0, b0, acc00, 0, 0, 0);
      acc01 = __builtin_amdgcn_mfma_f32_16x16x32_f16(a0, b1, acc01, 0, 0, 0);
      acc10 = __builtin_amdgcn_mfma_f32_16x16x32_f16(a1, b0, acc10, 0, 0, 0);
      acc11 = __builtin_amdgcn_mfma_f32_16x16x32_f16(a1, b1, acc11, 0, 0, 0);
    }
  }
  // epilogue: D mapping col=lane&15, row=(lane>>4)*4+j  [verified m89]
  int gq = lane >> 4, rr = lane & 15;
  f32x4 accs[2][2] = {{acc00, acc01}, {acc10, acc11}};
  #pragma unroll
  for (int mt = 0; mt < 2; mt++)
    #pragma unroll
    for (int nt = 0; nt < 2; nt++) {
      int row = m0 + wm * 32 + mt * 16 + gq * 4;
      int col = n0 + wn * 32 + nt * 16 + rr;
      float bv = bias0 ? bias0[col] : 0.f;
      if (bias1) bv += bias1[col];
      #pragma unroll
      for (int j = 0; j < 4; j++)
        out[(size_t)(row + j) * N + col] = accs[mt][nt][j] + bv;
    }
}

// ---------------- one LSTM step ----------------
// WG = 64 batches x (16 hidden x 4 gates). gates = xp + hprev @ Whh^T, then
// i,f,g,o activations, c/h update all WG-local. grid = 4 batch-blocks * 64 hid-blocks = 256.
__global__ __launch_bounds__(256) void lstm_step_kernel(
    const f16* __restrict__ hprev, const f16* __restrict__ Whh,
    const float* __restrict__ xp, float* __restrict__ cst,
    f16* __restrict__ hout)
{
  __shared__ __align__(16) f16 As[64][72];
  __shared__ __align__(16) f16 Bs[64][72];
  __shared__ float gsm[64][65];
  int bx = blockIdx.x;
  int hj = bx & 63;            // hidden block (16 hid)
  int m0 = (bx >> 6) * 64;     // batch block
  int tid = threadIdx.x;
  int lane = tid & 63, w = tid >> 6;
  int wm = w >> 1, wn = w & 1;
  int sr = tid >> 2, sseg = tid & 3;
  const f16* ga = hprev + (size_t)(m0 + sr) * LSTM_H + sseg * 16;
  int nrow = (sr >> 4) * LSTM_H + hj * 16 + (sr & 15);   // gate-major rows of Whh
  const f16* gb = Whh + (size_t)nrow * LSTM_H + sseg * 16;
  f32x4 acc00 = {}, acc01 = {}, acc10 = {}, acc11 = {};
  f16x8 ra0 = *(const f16x8*)ga, ra1 = *(const f16x8*)(ga + 8);
  f16x8 rb0 = *(const f16x8*)gb, rb1 = *(const f16x8*)(gb + 8);
  for (int kc = 0; kc < LSTM_H; kc += 64) {
    __syncthreads();
    *(f16x8*)&As[sr][sseg * 16]     = ra0;
    *(f16x8*)&As[sr][sseg * 16 + 8] = ra1;
    *(f16x8*)&Bs[sr][sseg * 16]     = rb0;
    *(f16x8*)&Bs[sr][sseg * 16 + 8] = rb1;
    __syncthreads();
    if (kc + 64 < LSTM_H) {
      ga += 64; gb += 64;
      ra0 = *(const f16x8*)ga; ra1 = *(const f16x8*)(ga + 8);
      rb0 = *(const f16x8*)gb; rb1 = *(const f16x8*)(gb + 8);
    }
    int g = lane >> 4, r = lane & 15;
    #pragma unroll
    for (int s = 0; s < 2; s++) {
      f16x8 a0 = *(const f16x8*)&As[wm * 32      + r][s * 32 + g * 8];
      f16x8 a1 = *(const f16x8*)&As[wm * 32 + 16 + r][s * 32 + g * 8];
      f16x8 b0 = *(const f16x8*)&Bs[wn * 32      + r][s * 32 + g * 8];
      f16x8 b1 = *(const f16x8*)&Bs[wn * 32 + 16 + r][s * 32 + g * 8];
      acc00 = __builtin_amdgcn_mfma_f32_16x16x32_f16(a0, b0, acc00, 0, 0, 0);
      acc01 = __builtin_amdgcn_mfma_f32_16x16x32_f16(a0, b1, acc01, 0, 0, 0);
      acc10 = __builtin_amdgcn_mfma_f32_16x16x32_f16(a1, b0, acc10, 0, 0, 0);
      acc11 = __builtin_amdgcn_mfma_f32_16x16x32_f16(a1, b1, acc11, 0, 0, 0);
    }
  }
  // stash gates tile to LDS
  {
    int gq = lane >> 4, rr = lane & 15;
    f32x4 accs[2][2] = {{acc00, acc01}, {acc10, acc11}};
    #pragma unroll
    for (int mt = 0; mt < 2; mt++)
      #pragma unroll
      for (int nt = 0; nt < 2; nt++)
        #pragma unroll
        for (int j = 0; j < 4; j++)
          gsm[wm * 32 + mt * 16 + gq * 4 + j][wn * 32 + nt * 16 + rr] = accs[mt][nt][j];
  }
  __syncthreads();
  // elementwise cell update: thread owns (b_loc, hh0*4..hh0*4+3)
  int b_loc = tid & 63, hh0 = tid >> 6;
  size_t rowb = (size_t)(m0 + b_loc);
  size_t xbase = rowb * GATES + hj * 16 + hh0 * 4;
  float4 xi = *(const float4*)&xp[xbase];
  float4 xf = *(const float4*)&xp[xbase + 1024];
  float4 xg = *(const float4*)&xp[xbase + 2048];
  float4 xo = *(const float4*)&xp[xbase + 3072];
  size_t cbase = rowb * LSTM_H + hj * 16 + hh0 * 4;
  float4 cv = *(const float4*)&cst[cbase];
  float xiv[4] = {xi.x, xi.y, xi.z, xi.w};
  float xfv[4] = {xf.x, xf.y, xf.z, xf.w};
  float xgv[4] = {xg.x, xg.y, xg.z, xg.w};
  float xov[4] = {xo.x, xo.y, xo.z, xo.w};
  float cvv[4] = {cv.x, cv.y, cv.z, cv.w};
  float hnew[4];
  #pragma unroll
  for (int u = 0; u < 4; u++) {
    int hh = hh0 * 4 + u;
    float iv = gsm[b_loc][hh]      + xiv[u];
    float fv = gsm[b_loc][16 + hh] + xfv[u];
    float gv = gsm[b_loc][32 + hh] + xgv[u];
    float ov = gsm[b_loc][48 + hh] + xov[u];
    iv = 1.f / (1.f + __expf(-iv));
    fv = 1.f / (1.f + __expf(-fv));
    gv = 2.f / (1.f + __expf(-2.f * gv)) - 1.f;   // tanh
    ov = 1.f / (1.f + __expf(-ov));
    float cn = fv * cvv[u] + iv * gv;
    cvv[u] = cn;
    float tc = 2.f / (1.f + __expf(-2.f * cn)) - 1.f;
    hnew[u] = ov * tc;
  }
  float4 cw; cw.x = cvv[0]; cw.y = cvv[1]; cw.z = cvv[2]; cw.w = cvv[3];
  *(float4*)&cst[cbase] = cw;
  f16x4 hw; hw[0] = (f16)hnew[0]; hw[1] = (f16)hnew[1]; hw[2] = (f16)hnew[2]; hw[3] = (f16)hnew[3];
  *(f16x4*)&hout[cbase] = hw;
}

extern "C" void kernel_launch(void* const* d_in, const int* in_sizes, int n_in,
                              void* d_out, int out_size, void* d_ws, size_t ws_size,
                              hipStream_t stream)
{
  (void)in_sizes; (void)n_in; (void)out_size;
  const float* C     = (const float*)d_in[0];
  const float* W_ih  = (const float*)d_in[1];
  const float* W_hh  = (const float*)d_in[2];
  const float* b_ih  = (const float*)d_in[3];
  const float* b_hh  = (const float*)d_in[4];
  const float* W_lin = (const float*)d_in[5];
  const float* b_lin = (const float*)d_in[6];
  // d_in[7] = max_seq_len (device scalar) — shape fixed, hardcode 128.

  char* ws = (char*)d_ws;
  size_t off = 0;
  auto alloc = [&](size_t bytes) { void* p = ws + off; off += (bytes + 255) & ~(size_t)255; return p; };
  f16*   Wih16  = (f16*)alloc((size_t)GATES * LSTM_H * 2);
  f16*   Whh16  = (f16*)alloc((size_t)GATES * LSTM_H * 2);
  f16*   Wlin16 = (f16*)alloc((size_t)LSTM_O * LSTM_H * 2);
  f16*   C16    = (f16*)alloc((size_t)LSTM_B * LSTM_H * 2);
  float* xp     = (float*)alloc((size_t)LSTM_B * GATES * 4);
  float* cbuf   = (float*)alloc((size_t)LSTM_B * LSTM_H * 4);
  f16*   h0     = (f16*)alloc((size_t)LSTM_B * LSTM_H * 2);
  size_t histB  = (size_t)LSTM_T * LSTM_B * LSTM_H * 2;
  bool batched = (off + histB) <= ws_size;     // deterministic per-call decision
  f16 *hist = nullptr, *ha = nullptr, *hb = nullptr;
  if (batched) hist = (f16*)alloc(histB);
  else { ha = (f16*)alloc((size_t)LSTM_B * LSTM_H * 2); hb = (f16*)alloc((size_t)LSTM_B * LSTM_H * 2); }

  cvt4_kernel<<<2048, 256, 0, stream>>>((const float4*)W_ih,  (f16x4*)Wih16,  GATES * LSTM_H / 4);
  cvt4_kernel<<<2048, 256, 0, stream>>>((const float4*)W_hh,  (f16x4*)Whh16,  GATES * LSTM_H / 4);
  cvt4_kernel<<<512,  256, 0, stream>>>((const float4*)W_lin, (f16x4*)Wlin16, LSTM_O * LSTM_H / 4);
  cvt4_kernel<<<256,  256, 0, stream>>>((const float4*)C,     (f16x4*)C16,    LSTM_B * LSTM_H / 4);
  hipMemsetAsync(cbuf, 0, (size_t)LSTM_B * LSTM_H * 4, stream);
  hipMemsetAsync(h0,   0, (size_t)LSTM_B * LSTM_H * 2, stream);

  // x_proj = C @ W_ih^T + b_ih + b_hh   (input constant across time -> once)
  gemm_bt_kernel<<<(LSTM_B / 64) * (GATES / 64), 256, 0, stream>>>(
      C16, Wih16, b_ih, b_hh, xp, LSTM_B, GATES, LSTM_H, GATES / 64);

  for (int t = 0; t < LSTM_T; t++) {
    const f16* hp = (t == 0) ? h0
                  : (batched ? hist + (size_t)(t - 1) * LSTM_B * LSTM_H
                             : ((t & 1) ? ha : hb));
    f16* ho = batched ? hist + (size_t)t * LSTM_B * LSTM_H
                      : ((t & 1) ? hb : ha);
    lstm_step_kernel<<<256, 256, 0, stream>>>(hp, Whh16, xp, cbuf, ho);
    if (!batched) {
      gemm_bt_kernel<<<(LSTM_B / 64) * (LSTM_O / 64), 256, 0, stream>>>(
          ho, Wlin16, b_lin, nullptr,
          (float*)d_out + (size_t)t * LSTM_B * LSTM_O, LSTM_B, LSTM_O, LSTM_H, LSTM_O / 64);
    }
  }
  if (batched) {
    // ys[t][b][o] in one big GEMM over the stored h history
    gemm_bt_kernel<<<(LSTM_T * LSTM_B / 64) * (LSTM_O / 64), 256, 0, stream>>>(
        hist, Wlin16, b_lin, nullptr, (float*)d_out,
        LSTM_T * LSTM_B, LSTM_O, LSTM_H, LSTM_O / 64);
  }
}